// Round 9
// baseline (482.392 us; speedup 1.0000x reference)
//
#include <hip/hip_runtime.h>
#include <hip/hip_bf16.h>
#include <stdint.h>

typedef __attribute__((ext_vector_type(8))) _Float16 half8;
typedef __attribute__((ext_vector_type(4))) float f32x4;
typedef __attribute__((ext_vector_type(16))) float f32x16;

#define N_TOK  65536
#define DIM    256
#define NT     76          // 32-cluster tiles: 69 (L0) + 6 (L1) + 1 (L2)
#define TAU    0.12f
#define MAXFL  8192        // per-layer flag cap

// padded layer map: L0 tiles [0,69) base 0 size 2197
//                   L1 tiles [69,75) base 2208 size 169
//                   L2 tile  75 base 2400 size 13

// workspace layout (bytes):
// 0       : int cnt[3] (per-layer flag counters)
// 64      : flag lists, 3 layers x 8192 int  (WS_FLAGS(L))
// 98368   : wnorm, 2432 floats (padded index)
// 131072  : fp16 hi W-frags, 76 tiles * 16KB
#define WS_FLAGS(L) (64 + (L) * 32768)
#define WS_WNORM    98368
#define WS_WHFRAG   131072

// -------- prep: pack W into 32x32x16 MFMA A-frag order (fp16 hi) + fp64 wnorm --
// frag slot q = s*64 + l  (s = K-step 0..15, l = lane): cluster = l&31,
// k = s*16 + (l>>5)*8 + j  (8 contiguous fp16 per lane)
__global__ void prep_kernel(const float* __restrict__ w0, const float* __restrict__ w1,
                            const float* __restrict__ w2, unsigned char* __restrict__ ws) {
  const int t = blockIdx.x;
  const int tid = threadIdx.x;           // 256 threads
  const float* wsrc; int basePad, csize;
  if (t < 69)      { wsrc = w0; basePad = 0;    csize = 2197; }
  else if (t < 75) { wsrc = w1; basePad = 2208; csize = 169;  }
  else             { wsrc = w2; basePad = 2400; csize = 13;   }
  half8* whf = (half8*)(ws + WS_WHFRAG);
#pragma unroll
  for (int r = 0; r < 4; ++r) {
    int q = r * 256 + tid;               // frag slot within tile
    int l = q & 63;
    int s = q >> 6;                      // 0..15
    int cit = l & 31;
    int k = s * 16 + (l >> 5) * 8;
    int cl = t * 32 + cit - basePad;
    float xs[8];
    if (cl < csize) {
      const float4* p = (const float4*)(wsrc + (size_t)cl * DIM + k);
      float4 a = p[0], b = p[1];
      xs[0]=a.x; xs[1]=a.y; xs[2]=a.z; xs[3]=a.w; xs[4]=b.x; xs[5]=b.y; xs[6]=b.z; xs[7]=b.w;
    } else {
#pragma unroll
      for (int j = 0; j < 8; ++j) xs[j] = 0.0f;
    }
    half8 h;
#pragma unroll
    for (int j = 0; j < 8; ++j) h[j] = (_Float16)xs[j];
    whf[(size_t)t * 1024 + q] = h;
  }
  // wnorm: 8 threads per cluster, fp64, shuffle-reduce
  {
    int gid = tid >> 3, j = tid & 7;     // gid 0..31
    int cl = t * 32 + gid - basePad;
    double acc = 0.0;
    if (cl >= 0 && cl < csize) {
      const float* row = wsrc + (size_t)cl * DIM + j * 32;
#pragma unroll
      for (int k = 0; k < 32; ++k) { double x = row[k]; acc += x * x; }
    }
    acc += __shfl_xor(acc, 1, 64);
    acc += __shfl_xor(acc, 2, 64);
    acc += __shfl_xor(acc, 4, 64);
    if (j == 0) {
      float* wn = (float*)(ws + WS_WNORM);
      wn[t * 32 + gid] = (cl >= 0 && cl < csize) ? (float)acc : __builtin_inff();
    }
  }
  if (t == 0 && tid < 3) ((int*)ws)[tid] = 0;
}

// -------- main: 64 tok/wave (2 MFMA B-groups), barrier-free A/B streaming -----
__global__ __launch_bounds__(128, 1) void argmin_kernel(
    const float* __restrict__ E, const float* __restrict__ w0, const float* __restrict__ w1,
    const float* __restrict__ w2, float* __restrict__ out, unsigned char* __restrict__ ws) {
  const int tid   = threadIdx.x;
  const int lane  = tid & 63;
  const int wave  = tid >> 6;    // 0..1
  const int col   = lane & 31;   // token within 32-tile
  const int khalf = lane >> 5;   // 0/1 (k sub-block / C-row offset)
  const int tokA  = blockIdx.x * 128 + wave * 64;   // group A token base
  const int tokB  = tokA + 32;                      // group B token base

  // E fragments (B-operand): lane holds E[tok=base+col][k = s*16 + khalf*8 + j]
  half8 ehA[16], ehB[16];
#pragma unroll
  for (int s = 0; s < 16; ++s) {
    {
      const float4* p = (const float4*)(E + (size_t)(tokA + col) * DIM + s * 16 + khalf * 8);
      float4 a = p[0], b = p[1];
      float xs[8] = {a.x, a.y, a.z, a.w, b.x, b.y, b.z, b.w};
      half8 h;
#pragma unroll
      for (int j = 0; j < 8; ++j) h[j] = (_Float16)xs[j];
      ehA[s] = h;
    }
    {
      const float4* p = (const float4*)(E + (size_t)(tokB + col) * DIM + s * 16 + khalf * 8);
      float4 a = p[0], b = p[1];
      float xs[8] = {a.x, a.y, a.z, a.w, b.x, b.y, b.z, b.w};
      half8 h;
#pragma unroll
      for (int j = 0; j < 8; ++j) h[j] = (_Float16)xs[j];
      ehB[s] = h;
    }
  }

  const half8* whf = (const half8*)(ws + WS_WHFRAG);
  const float* wn  = (const float*)(ws + WS_WNORM);

  float v1A = __builtin_inff(), v2A = __builtin_inff();
  float v1B = __builtin_inff(), v2B = __builtin_inff();
  int   i1A = 0x7fffffff, i1B = 0x7fffffff;

#define LOADW(DST, T) { const half8* p_ = whf + (size_t)(T) * 1024; _Pragma("unroll") \
    for (int s = 0; s < 16; ++s) DST[s] = p_[s * 64 + lane]; }

  // two independent MFMA chains (groups A/B share W frags) + fused epilogue
#define TILE(REGS, T)                                                        \
  {                                                                          \
    f32x16 aA = (f32x16){0.f,0.f,0.f,0.f,0.f,0.f,0.f,0.f,                    \
                         0.f,0.f,0.f,0.f,0.f,0.f,0.f,0.f};                   \
    f32x16 aB = aA;                                                          \
    _Pragma("unroll")                                                        \
    for (int s = 0; s < 16; ++s) {                                           \
      aA = __builtin_amdgcn_mfma_f32_32x32x16_f16(REGS[s], ehA[s], aA, 0, 0, 0); \
      aB = __builtin_amdgcn_mfma_f32_32x32x16_f16(REGS[s], ehB[s], aB, 0, 0, 0); \
    }                                                                        \
    _Pragma("unroll")                                                        \
    for (int q = 0; q < 4; ++q) {                                            \
      float4 w4 = *(const float4*)(wn + (T) * 32 + q * 8 + khalf * 4);       \
      float wv[4] = {w4.x, w4.y, w4.z, w4.w};                                \
      _Pragma("unroll")                                                      \
      for (int rr = 0; rr < 4; ++rr) {                                       \
        int c = (T) * 32 + rr + 8 * q + 4 * khalf;                           \
        { float d = __builtin_fmaf(-2.0f, aA[q * 4 + rr], wv[rr]);           \
          bool lt = d < v1A; float hi = fmaxf(d, v1A);                       \
          v1A = fminf(d, v1A); v2A = fminf(v2A, hi); i1A = lt ? c : i1A; }   \
        { float d = __builtin_fmaf(-2.0f, aB[q * 4 + rr], wv[rr]);           \
          bool lt = d < v1B; float hi = fmaxf(d, v1B);                       \
          v1B = fminf(d, v1B); v2B = fminf(v2B, hi); i1B = lt ? c : i1B; }   \
      }                                                                      \
    }                                                                        \
  }

  // per-group finalize: khalf merge, near-tie flag (per-layer list), row write
#define FIN1(LVAL, BASEPAD, WLP, V1, V2, I1, TB)                             \
  {                                                                          \
    float o1 = __shfl_xor(V1, 32, 64);                                       \
    int   oi = __shfl_xor(I1, 32, 64);                                       \
    float o2 = __shfl_xor(V2, 32, 64);                                       \
    float a1 = fminf(V1, o1);                                                \
    float a2 = fminf(fmaxf(V1, o1), fminf(V2, o2));                          \
    int   b1 = (o1 < V1) ? oi : I1;                                          \
    int li = b1 - (BASEPAD);                                                 \
    if (khalf == 0 && (a2 - a1 < TAU)) {                                     \
      int pos = atomicAdd((int*)ws + (LVAL), 1);                             \
      if (pos < MAXFL) ((int*)(ws + WS_FLAGS(LVAL)))[pos] = (TB) + col;      \
    }                                                                        \
    _Pragma("unroll 1")                                                      \
    for (int r = 0; r < 32; ++r) {                                           \
      int ir = __shfl(li, r, 64);                                            \
      const f32x4* src = (const f32x4*)((WLP) + (size_t)ir * DIM);           \
      f32x4* dst = (f32x4*)(out + ((size_t)((LVAL) * N_TOK + (TB) + r)) * DIM); \
      __builtin_nontemporal_store(src[lane], &dst[lane]);                    \
    }                                                                        \
    V1 = __builtin_inff(); V2 = __builtin_inff(); I1 = 0x7fffffff;           \
  }

  half8 wA[16], wB[16];
  LOADW(wA, 0);

#pragma unroll 1
  for (int it = 0; it < NT / 2; ++it) {
    const int t0 = 2 * it, t1 = t0 + 1;
    LOADW(wB, t1);
    TILE(wA, t0);
    if (t0 == 68) { FIN1(0, 0, w0, v1A, v2A, i1A, tokA); FIN1(0, 0, w0, v1B, v2B, i1B, tokB); }
    if (t0 == 74) { FIN1(1, 2208, w1, v1A, v2A, i1A, tokA); FIN1(1, 2208, w1, v1B, v2B, i1B, tokB); }
    if (it + 1 < NT / 2) LOADW(wA, t0 + 2);
    TILE(wB, t1);
    if (t1 == 75) { FIN1(2, 2400, w2, v1A, v2A, i1A, tokA); FIN1(2, 2400, w2, v1B, v2B, i1B, tokB); }
  }
#undef LOADW
#undef TILE
#undef FIN1
}

// ------- refine: 8 flags/block, E-row in registers, W read once per group ----
// thread = (row-slot r = tid>>3 in 0..31, token j = tid&7). Full-dim local
// accumulation (no per-row cross-lane reduce). fp32 dot-form with 4 partials
// (err ~1e-4, << resolved-gap scale); wnorm is the prep fp64 norm.
__global__ __launch_bounds__(256, 1) void refine_kernel(
    const float* __restrict__ E, const float* __restrict__ w0,
    const float* __restrict__ w1, const float* __restrict__ w2,
    float* __restrict__ out, unsigned char* __restrict__ ws) {
  const int tid  = threadIdx.x;
  const int lane = tid & 63;
  const int wave = tid >> 6;
  const int r    = tid >> 3;   // 0..31 row slot
  const int j    = tid & 7;    // token within group
  const int* cnt = (const int*)ws;
  int c0 = cnt[0] < MAXFL ? cnt[0] : MAXFL;
  int c1 = cnt[1] < MAXFL ? cnt[1] : MAXFL;
  int c2 = cnt[2] < MAXFL ? cnt[2] : MAXFL;
  int g0 = (c0 + 7) >> 3, g1 = (c1 + 7) >> 3, g2 = (c2 + 7) >> 3;
  int gtot = g0 + g1 + g2;
  const float* wn = (const float*)(ws + WS_WNORM);

  __shared__ int   toks[8];
  __shared__ float redd[4][8];
  __shared__ int   redi[4][8];
  __shared__ int   winner[8];

  for (int gid = blockIdx.x; gid < gtot; gid += gridDim.x) {
    int L, gi, cl, csize, basePad; const float* WL;
    if (gid < g0)           { L = 0; gi = gid;           cl = c0; WL = w0; csize = 2197; basePad = 0; }
    else if (gid < g0 + g1) { L = 1; gi = gid - g0;      cl = c1; WL = w1; csize = 169;  basePad = 2208; }
    else                    { L = 2; gi = gid - g0 - g1; cl = c2; WL = w2; csize = 13;   basePad = 2400; }
    const int* fl = (const int*)(ws + WS_FLAGS(L)) + gi * 8;
    const int m = (cl - gi * 8 < 8) ? (cl - gi * 8) : 8;
    __syncthreads();                       // protect shared reuse across groups
    if (tid < 8) toks[tid] = fl[(tid < m) ? tid : 0];
    __syncthreads();
    // E row of token j into registers (64 float4), + enorm
    f32x4 er[64];
    {
      const f32x4* ep = (const f32x4*)(E + (size_t)toks[j] * DIM);
#pragma unroll
      for (int p = 0; p < 64; ++p) er[p] = ep[p];
    }
    float en;
    {
      float e0 = 0.f, e1 = 0.f, e2 = 0.f, e3 = 0.f;
#pragma unroll
      for (int p = 0; p < 64; p += 4) {
        e0 = __builtin_fmaf(er[p].x, er[p].x, __builtin_fmaf(er[p].y, er[p].y,
             __builtin_fmaf(er[p].z, er[p].z, __builtin_fmaf(er[p].w, er[p].w, e0))));
        e1 = __builtin_fmaf(er[p+1].x, er[p+1].x, __builtin_fmaf(er[p+1].y, er[p+1].y,
             __builtin_fmaf(er[p+1].z, er[p+1].z, __builtin_fmaf(er[p+1].w, er[p+1].w, e1))));
        e2 = __builtin_fmaf(er[p+2].x, er[p+2].x, __builtin_fmaf(er[p+2].y, er[p+2].y,
             __builtin_fmaf(er[p+2].z, er[p+2].z, __builtin_fmaf(er[p+2].w, er[p+2].w, e2))));
        e3 = __builtin_fmaf(er[p+3].x, er[p+3].x, __builtin_fmaf(er[p+3].y, er[p+3].y,
             __builtin_fmaf(er[p+3].z, er[p+3].z, __builtin_fmaf(er[p+3].w, er[p+3].w, e3))));
      }
      en = (e0 + e1) + (e2 + e3);
    }
    float bd = __builtin_inff(); int bi = 0x7fffffff;
#pragma unroll 1
    for (int cb = 0; cb < csize; cb += 32) {
      int c = cb + r;
      bool ok = c < csize;
      const f32x4* row = (const f32x4*)(WL + (size_t)(ok ? c : 0) * DIM);
      float s0 = 0.f, s1 = 0.f, s2 = 0.f, s3 = 0.f;
#pragma unroll
      for (int p = 0; p < 64; p += 4) {
        f32x4 a = row[p], b = row[p+1], cc = row[p+2], dd = row[p+3];
        s0 = __builtin_fmaf(a.x, er[p].x, __builtin_fmaf(a.y, er[p].y,
             __builtin_fmaf(a.z, er[p].z, __builtin_fmaf(a.w, er[p].w, s0))));
        s1 = __builtin_fmaf(b.x, er[p+1].x, __builtin_fmaf(b.y, er[p+1].y,
             __builtin_fmaf(b.z, er[p+1].z, __builtin_fmaf(b.w, er[p+1].w, s1))));
        s2 = __builtin_fmaf(cc.x, er[p+2].x, __builtin_fmaf(cc.y, er[p+2].y,
             __builtin_fmaf(cc.z, er[p+2].z, __builtin_fmaf(cc.w, er[p+2].w, s2))));
        s3 = __builtin_fmaf(dd.x, er[p+3].x, __builtin_fmaf(dd.y, er[p+3].y,
             __builtin_fmaf(dd.z, er[p+3].z, __builtin_fmaf(dd.w, er[p+3].w, s3))));
      }
      float dot = (s0 + s1) + (s2 + s3);
      float d = ok ? (wn[basePad + c] + en - 2.0f * dot) : __builtin_inff();
      bool lt = (d < bd) || (d == bd && c < bi);
      bd = lt ? d : bd; bi = lt ? c : bi;
    }
    // merge row-slots within wave: lanes {j, j+8, ..., j+56}
#pragma unroll
    for (int off = 8; off <= 32; off <<= 1) {
      float od = __shfl_xor(bd, off, 64);
      int   oi = __shfl_xor(bi, off, 64);
      bool take = (od < bd) || (od == bd && oi < bi);
      bd = take ? od : bd; bi = take ? oi : bi;
    }
    if (lane < 8) { redd[wave][lane] = bd; redi[wave][lane] = bi; }
    __syncthreads();
    if (tid < 8) {
      float b = redd[0][tid]; int x = redi[0][tid];
#pragma unroll
      for (int w = 1; w < 4; ++w) {
        if (redd[w][tid] < b || (redd[w][tid] == b && redi[w][tid] < x)) { b = redd[w][tid]; x = redi[w][tid]; }
      }
      winner[tid] = x;
    }
    __syncthreads();
    // gather winner rows: thread writes token (tid>>5), dims [(tid&31)*8, +8)
    {
      int wj = tid >> 5, dbase = (tid & 31) * 8;
      if (wj < m) {
        const f32x4* src = (const f32x4*)(WL + (size_t)winner[wj] * DIM + dbase);
        f32x4* dst = (f32x4*)(out + ((size_t)(L * N_TOK + toks[wj])) * DIM + dbase);
        dst[0] = src[0]; dst[1] = src[1];
      }
    }
  }
}

extern "C" void kernel_launch(void* const* d_in, const int* in_sizes, int n_in,
                              void* d_out, int out_size, void* d_ws, size_t ws_size,
                              hipStream_t stream) {
  const float* E  = (const float*)d_in[0];
  const float* w0 = (const float*)d_in[1];
  const float* w1 = (const float*)d_in[2];
  const float* w2 = (const float*)d_in[3];
  float* out = (float*)d_out;
  unsigned char* ws = (unsigned char*)d_ws;

  hipLaunchKernelGGL(prep_kernel,   dim3(NT),  dim3(256), 0, stream, w0, w1, w2, ws);
  hipLaunchKernelGGL(argmin_kernel, dim3(512), dim3(128), 0, stream, E, w0, w1, w2, out, ws);
  hipLaunchKernelGGL(refine_kernel, dim3(512), dim3(256), 0, stream, E, w0, w1, w2, out, ws);
}

// Round 10
// 413.164 us; speedup vs baseline: 1.1676x; 1.1676x over previous
//
#include <hip/hip_runtime.h>
#include <hip/hip_bf16.h>
#include <stdint.h>

typedef __attribute__((ext_vector_type(8))) _Float16 half8;
typedef __attribute__((ext_vector_type(4))) float f32x4;
typedef __attribute__((ext_vector_type(16))) float f32x16;

#define N_TOK  65536
#define DIM    256
#define NT     76          // 32-cluster tiles: 69 (L0) + 6 (L1) + 1 (L2)
#define TAU    0.12f
#define MAXFL  8192        // per-layer flag cap

// padded layer map: L0 tiles [0,69) base 0 size 2197
//                   L1 tiles [69,75) base 2208 size 169
//                   L2 tile  75 base 2400 size 13

// workspace layout (bytes):
// 0       : int cnt[3] (per-layer flag counters)
// 64      : flag lists, 3 layers x 8192 int  (WS_FLAGS(L))
// 98368   : wnorm, 2432 floats (padded index)
// 131072  : fp16 hi W-frags, 76 tiles * 16KB
#define WS_FLAGS(L) (64 + (L) * 32768)
#define WS_WNORM    98368
#define WS_WHFRAG   131072

// -------- prep: pack W into 32x32x16 MFMA A-frag order (fp16 hi) + fp64 wnorm --
__global__ void prep_kernel(const float* __restrict__ w0, const float* __restrict__ w1,
                            const float* __restrict__ w2, unsigned char* __restrict__ ws) {
  const int t = blockIdx.x;
  const int tid = threadIdx.x;           // 256 threads
  const float* wsrc; int basePad, csize;
  if (t < 69)      { wsrc = w0; basePad = 0;    csize = 2197; }
  else if (t < 75) { wsrc = w1; basePad = 2208; csize = 169;  }
  else             { wsrc = w2; basePad = 2400; csize = 13;   }
  half8* whf = (half8*)(ws + WS_WHFRAG);
#pragma unroll
  for (int r = 0; r < 4; ++r) {
    int q = r * 256 + tid;               // frag slot within tile
    int l = q & 63;
    int s = q >> 6;                      // 0..15
    int cit = l & 31;
    int k = s * 16 + (l >> 5) * 8;
    int cl = t * 32 + cit - basePad;
    float xs[8];
    if (cl < csize) {
      const float4* p = (const float4*)(wsrc + (size_t)cl * DIM + k);
      float4 a = p[0], b = p[1];
      xs[0]=a.x; xs[1]=a.y; xs[2]=a.z; xs[3]=a.w; xs[4]=b.x; xs[5]=b.y; xs[6]=b.z; xs[7]=b.w;
    } else {
#pragma unroll
      for (int j = 0; j < 8; ++j) xs[j] = 0.0f;
    }
    half8 h;
#pragma unroll
    for (int j = 0; j < 8; ++j) h[j] = (_Float16)xs[j];
    whf[(size_t)t * 1024 + q] = h;
  }
  // wnorm: 8 threads per cluster, fp64, shuffle-reduce
  {
    int gid = tid >> 3, j = tid & 7;     // gid 0..31
    int cl = t * 32 + gid - basePad;
    double acc = 0.0;
    if (cl >= 0 && cl < csize) {
      const float* row = wsrc + (size_t)cl * DIM + j * 32;
#pragma unroll
      for (int k = 0; k < 32; ++k) { double x = row[k]; acc += x * x; }
    }
    acc += __shfl_xor(acc, 1, 64);
    acc += __shfl_xor(acc, 2, 64);
    acc += __shfl_xor(acc, 4, 64);
    if (j == 0) {
      float* wn = (float*)(ws + WS_WNORM);
      wn[t * 32 + gid] = (cl >= 0 && cl < csize) ? (float)acc : __builtin_inff();
    }
  }
  if (t == 0 && tid < 3) ((int*)ws)[tid] = 0;
}

// -------- main: 64 tok/wave (2 MFMA B-groups), barrier-free A/B streaming -----
__global__ __launch_bounds__(128, 1) void argmin_kernel(
    const float* __restrict__ E, const float* __restrict__ w0, const float* __restrict__ w1,
    const float* __restrict__ w2, float* __restrict__ out, unsigned char* __restrict__ ws) {
  const int tid   = threadIdx.x;
  const int lane  = tid & 63;
  const int wave  = tid >> 6;    // 0..1
  const int col   = lane & 31;   // token within 32-tile
  const int khalf = lane >> 5;   // 0/1 (k sub-block / C-row offset)
  const int tokA  = blockIdx.x * 128 + wave * 64;   // group A token base
  const int tokB  = tokA + 32;                      // group B token base

  // E fragments (B-operand): lane holds E[tok=base+col][k = s*16 + khalf*8 + j]
  half8 ehA[16], ehB[16];
#pragma unroll
  for (int s = 0; s < 16; ++s) {
    {
      const float4* p = (const float4*)(E + (size_t)(tokA + col) * DIM + s * 16 + khalf * 8);
      float4 a = p[0], b = p[1];
      float xs[8] = {a.x, a.y, a.z, a.w, b.x, b.y, b.z, b.w};
      half8 h;
#pragma unroll
      for (int j = 0; j < 8; ++j) h[j] = (_Float16)xs[j];
      ehA[s] = h;
    }
    {
      const float4* p = (const float4*)(E + (size_t)(tokB + col) * DIM + s * 16 + khalf * 8);
      float4 a = p[0], b = p[1];
      float xs[8] = {a.x, a.y, a.z, a.w, b.x, b.y, b.z, b.w};
      half8 h;
#pragma unroll
      for (int j = 0; j < 8; ++j) h[j] = (_Float16)xs[j];
      ehB[s] = h;
    }
  }

  const half8* whf = (const half8*)(ws + WS_WHFRAG);
  const float* wn  = (const float*)(ws + WS_WNORM);

  float v1A = __builtin_inff(), v2A = __builtin_inff();
  float v1B = __builtin_inff(), v2B = __builtin_inff();
  int   i1A = 0x7fffffff, i1B = 0x7fffffff;

#define LOADW(DST, T) { const half8* p_ = whf + (size_t)(T) * 1024; _Pragma("unroll") \
    for (int s = 0; s < 16; ++s) DST[s] = p_[s * 64 + lane]; }

  // two independent MFMA chains (groups A/B share W frags) + fused epilogue
#define TILE(REGS, T)                                                        \
  {                                                                          \
    f32x16 aA = (f32x16){0.f,0.f,0.f,0.f,0.f,0.f,0.f,0.f,                    \
                         0.f,0.f,0.f,0.f,0.f,0.f,0.f,0.f};                   \
    f32x16 aB = aA;                                                          \
    _Pragma("unroll")                                                        \
    for (int s = 0; s < 16; ++s) {                                           \
      aA = __builtin_amdgcn_mfma_f32_32x32x16_f16(REGS[s], ehA[s], aA, 0, 0, 0); \
      aB = __builtin_amdgcn_mfma_f32_32x32x16_f16(REGS[s], ehB[s], aB, 0, 0, 0); \
    }                                                                        \
    _Pragma("unroll")                                                        \
    for (int q = 0; q < 4; ++q) {                                            \
      float4 w4 = *(const float4*)(wn + (T) * 32 + q * 8 + khalf * 4);       \
      float wv[4] = {w4.x, w4.y, w4.z, w4.w};                                \
      _Pragma("unroll")                                                      \
      for (int rr = 0; rr < 4; ++rr) {                                       \
        int c = (T) * 32 + rr + 8 * q + 4 * khalf;                           \
        { float d = __builtin_fmaf(-2.0f, aA[q * 4 + rr], wv[rr]);           \
          bool lt = d < v1A; float hi = fmaxf(d, v1A);                       \
          v1A = fminf(d, v1A); v2A = fminf(v2A, hi); i1A = lt ? c : i1A; }   \
        { float d = __builtin_fmaf(-2.0f, aB[q * 4 + rr], wv[rr]);           \
          bool lt = d < v1B; float hi = fmaxf(d, v1B);                       \
          v1B = fminf(d, v1B); v2B = fminf(v2B, hi); i1B = lt ? c : i1B; }   \
      }                                                                      \
    }                                                                        \
  }

  // per-group finalize: khalf merge, near-tie flag (per-layer list), row write
#define FIN1(LVAL, BASEPAD, WLP, V1, V2, I1, TB)                             \
  {                                                                          \
    float o1 = __shfl_xor(V1, 32, 64);                                       \
    int   oi = __shfl_xor(I1, 32, 64);                                       \
    float o2 = __shfl_xor(V2, 32, 64);                                       \
    float a1 = fminf(V1, o1);                                                \
    float a2 = fminf(fmaxf(V1, o1), fminf(V2, o2));                          \
    int   b1 = (o1 < V1) ? oi : I1;                                          \
    int li = b1 - (BASEPAD);                                                 \
    if (khalf == 0 && (a2 - a1 < TAU)) {                                     \
      int pos = atomicAdd((int*)ws + (LVAL), 1);                             \
      if (pos < MAXFL) ((int*)(ws + WS_FLAGS(LVAL)))[pos] = (TB) + col;      \
    }                                                                        \
    _Pragma("unroll 1")                                                      \
    for (int r = 0; r < 32; ++r) {                                           \
      int ir = __shfl(li, r, 64);                                            \
      const f32x4* src = (const f32x4*)((WLP) + (size_t)ir * DIM);           \
      f32x4* dst = (f32x4*)(out + ((size_t)((LVAL) * N_TOK + (TB) + r)) * DIM); \
      __builtin_nontemporal_store(src[lane], &dst[lane]);                    \
    }                                                                        \
    V1 = __builtin_inff(); V2 = __builtin_inff(); I1 = 0x7fffffff;           \
  }

  half8 wA[16], wB[16];
  LOADW(wA, 0);

#pragma unroll 1
  for (int it = 0; it < NT / 2; ++it) {
    const int t0 = 2 * it, t1 = t0 + 1;
    LOADW(wB, t1);
    TILE(wA, t0);
    if (t0 == 68) { FIN1(0, 0, w0, v1A, v2A, i1A, tokA); FIN1(0, 0, w0, v1B, v2B, i1B, tokB); }
    if (t0 == 74) { FIN1(1, 2208, w1, v1A, v2A, i1A, tokA); FIN1(1, 2208, w1, v1B, v2B, i1B, tokB); }
    if (it + 1 < NT / 2) LOADW(wA, t0 + 2);
    TILE(wB, t1);
    if (t1 == 75) { FIN1(2, 2400, w2, v1A, v2A, i1A, tokA); FIN1(2, 2400, w2, v1B, v2B, i1B, tokB); }
  }
#undef LOADW
#undef TILE
#undef FIN1
}

// ------- refine: 8 flags/group; E half-rows in registers (no spill) ----------
// thread = (row-slot r = tid>>4 in 0..15, half h = (tid>>3)&1, token j = tid&7).
// Each thread: 128-dim E chunk in 32 f32x4 regs; per row computes 128-dim
// partial dot; shfl_xor(.,8) combines halves. W rows stream from L2, 8-way
// same-address broadcast across j lanes. fp32 dot-form (validated R8/R9).
__global__ __launch_bounds__(256, 1) void refine_kernel(
    const float* __restrict__ E, const float* __restrict__ w0,
    const float* __restrict__ w1, const float* __restrict__ w2,
    float* __restrict__ out, unsigned char* __restrict__ ws) {
  const int tid  = threadIdx.x;
  const int lane = tid & 63;
  const int wave = tid >> 6;
  const int r    = tid >> 4;          // 0..15 row slot
  const int h    = (tid >> 3) & 1;    // E/W half
  const int j    = tid & 7;           // token within group
  const int* cnt = (const int*)ws;
  int c0 = cnt[0] < MAXFL ? cnt[0] : MAXFL;
  int c1 = cnt[1] < MAXFL ? cnt[1] : MAXFL;
  int c2 = cnt[2] < MAXFL ? cnt[2] : MAXFL;
  int g0 = (c0 + 7) >> 3, g1 = (c1 + 7) >> 3, g2 = (c2 + 7) >> 3;
  int gtot = g0 + g1 + g2;
  const float* wn = (const float*)(ws + WS_WNORM);

  __shared__ int   toks[8];
  __shared__ float redd[4][16];
  __shared__ int   redi[4][16];
  __shared__ int   winner[8];

  for (int gid = blockIdx.x; gid < gtot; gid += gridDim.x) {
    int L, gi, cl, csize, basePad; const float* WL;
    if (gid < g0)           { L = 0; gi = gid;           cl = c0; WL = w0; csize = 2197; basePad = 0; }
    else if (gid < g0 + g1) { L = 1; gi = gid - g0;      cl = c1; WL = w1; csize = 169;  basePad = 2208; }
    else                    { L = 2; gi = gid - g0 - g1; cl = c2; WL = w2; csize = 13;   basePad = 2400; }
    const int* fl = (const int*)(ws + WS_FLAGS(L)) + gi * 8;
    const int m = (cl - gi * 8 < 8) ? (cl - gi * 8) : 8;
    __syncthreads();                       // protect shared reuse across groups
    if (tid < 8) toks[tid] = fl[(tid < 8 && tid < m) ? tid : 0];
    __syncthreads();
    // E half-row of token j into registers (32 f32x4 = 128 VGPR)
    f32x4 er[32];
    {
      const f32x4* ep = (const f32x4*)(E + (size_t)toks[j] * DIM + h * 128);
#pragma unroll
      for (int p = 0; p < 32; ++p) er[p] = ep[p];
    }
    float en;
    {
      float e0 = 0.f, e1 = 0.f, e2 = 0.f, e3 = 0.f;
#pragma unroll
      for (int p = 0; p < 32; p += 4) {
        e0 = __builtin_fmaf(er[p].x, er[p].x, __builtin_fmaf(er[p].y, er[p].y,
             __builtin_fmaf(er[p].z, er[p].z, __builtin_fmaf(er[p].w, er[p].w, e0))));
        e1 = __builtin_fmaf(er[p+1].x, er[p+1].x, __builtin_fmaf(er[p+1].y, er[p+1].y,
             __builtin_fmaf(er[p+1].z, er[p+1].z, __builtin_fmaf(er[p+1].w, er[p+1].w, e1))));
        e2 = __builtin_fmaf(er[p+2].x, er[p+2].x, __builtin_fmaf(er[p+2].y, er[p+2].y,
             __builtin_fmaf(er[p+2].z, er[p+2].z, __builtin_fmaf(er[p+2].w, er[p+2].w, e2))));
        e3 = __builtin_fmaf(er[p+3].x, er[p+3].x, __builtin_fmaf(er[p+3].y, er[p+3].y,
             __builtin_fmaf(er[p+3].z, er[p+3].z, __builtin_fmaf(er[p+3].w, er[p+3].w, e3))));
      }
      float enp = (e0 + e1) + (e2 + e3);
      en = enp + __shfl_xor(enp, 8, 64);   // combine halves (partner lane^8)
    }
    float bd = __builtin_inff(); int bi = 0x7fffffff;
#pragma unroll 1
    for (int cb = 0; cb < csize; cb += 16) {
      int c = cb + r;
      bool ok = c < csize;
      const f32x4* row = (const f32x4*)(WL + (size_t)(ok ? c : 0) * DIM + h * 128);
      float s0 = 0.f, s1 = 0.f, s2 = 0.f, s3 = 0.f;
#pragma unroll
      for (int p = 0; p < 32; p += 4) {
        f32x4 a = row[p], b = row[p+1], cc = row[p+2], dd = row[p+3];
        s0 = __builtin_fmaf(a.x, er[p].x, __builtin_fmaf(a.y, er[p].y,
             __builtin_fmaf(a.z, er[p].z, __builtin_fmaf(a.w, er[p].w, s0))));
        s1 = __builtin_fmaf(b.x, er[p+1].x, __builtin_fmaf(b.y, er[p+1].y,
             __builtin_fmaf(b.z, er[p+1].z, __builtin_fmaf(b.w, er[p+1].w, s1))));
        s2 = __builtin_fmaf(cc.x, er[p+2].x, __builtin_fmaf(cc.y, er[p+2].y,
             __builtin_fmaf(cc.z, er[p+2].z, __builtin_fmaf(cc.w, er[p+2].w, s2))));
        s3 = __builtin_fmaf(dd.x, er[p+3].x, __builtin_fmaf(dd.y, er[p+3].y,
             __builtin_fmaf(dd.z, er[p+3].z, __builtin_fmaf(dd.w, er[p+3].w, s3))));
      }
      float dp = (s0 + s1) + (s2 + s3);
      float dot = dp + __shfl_xor(dp, 8, 64);    // both partners get same sum
      float d = ok ? (wn[basePad + c] + en - 2.0f * dot) : __builtin_inff();
      bool lt = (d < bd) || (d == bd && c < bi);
      bd = lt ? d : bd; bi = lt ? c : bi;
    }
    // merge row-slots: r low 2 bits within wave (lane^16, lane^32)
#pragma unroll
    for (int off = 16; off <= 32; off <<= 1) {
      float od = __shfl_xor(bd, off, 64);
      int   oi = __shfl_xor(bi, off, 64);
      bool take = (od < bd) || (od == bd && oi < bi);
      bd = take ? od : bd; bi = take ? oi : bi;
    }
    if (lane < 16) { redd[wave][lane] = bd; redi[wave][lane] = bi; }
    __syncthreads();
    if (tid < 8) {
      float b = redd[0][tid]; int x = redi[0][tid];
#pragma unroll
      for (int w = 1; w < 4; ++w) {
        if (redd[w][tid] < b || (redd[w][tid] == b && redi[w][tid] < x)) { b = redd[w][tid]; x = redi[w][tid]; }
      }
      winner[tid] = x;
    }
    __syncthreads();
    // gather winner rows: thread writes token (tid>>5), dims [(tid&31)*8, +8)
    {
      int wj = tid >> 5, dbase = (tid & 31) * 8;
      if (wj < m) {
        const f32x4* src = (const f32x4*)(WL + (size_t)winner[wj] * DIM + dbase);
        f32x4* dst = (f32x4*)(out + ((size_t)(L * N_TOK + toks[wj])) * DIM + dbase);
        dst[0] = src[0]; dst[1] = src[1];
      }
    }
  }
}

extern "C" void kernel_launch(void* const* d_in, const int* in_sizes, int n_in,
                              void* d_out, int out_size, void* d_ws, size_t ws_size,
                              hipStream_t stream) {
  const float* E  = (const float*)d_in[0];
  const float* w0 = (const float*)d_in[1];
  const float* w1 = (const float*)d_in[2];
  const float* w2 = (const float*)d_in[3];
  float* out = (float*)d_out;
  unsigned char* ws = (unsigned char*)d_ws;

  hipLaunchKernelGGL(prep_kernel,   dim3(NT),  dim3(256), 0, stream, w0, w1, w2, ws);
  hipLaunchKernelGGL(argmin_kernel, dim3(512), dim3(128), 0, stream, E, w0, w1, w2, out, ws);
  hipLaunchKernelGGL(refine_kernel, dim3(512), dim3(256), 0, stream, E, w0, w1, w2, out, ws);
}